// Round 5
// baseline (1686.552 us; speedup 1.0000x reference)
//
#include <hip/hip_runtime.h>
#include <math.h>

#define B_ 32
#define T_ 200
#define D_ 256
#define H_ 4
#define DH_ 32
#define INNER_ 128
#define L_ 8
#define FF_ 1024
#define NI_ 100000
#define NB_ 64
#define CH_ 25

typedef __attribute__((ext_vector_type(8))) short short8;
typedef __attribute__((ext_vector_type(8))) unsigned short ushort8;
typedef __attribute__((ext_vector_type(4))) unsigned short ushort4v;
typedef __attribute__((ext_vector_type(4))) float floatx4;

__device__ __forceinline__ float gelu_f(float x){
  return 0.5f*x*(1.0f+erff(x*0.70710678118654752f));
}
__device__ __forceinline__ float wsum(float v){
  #pragma unroll
  for (int o=32;o>0;o>>=1) v += __shfl_xor(v,o,64);
  return v;
}
__device__ __forceinline__ unsigned short f2bf(float x){
  unsigned int u = __float_as_uint(x);
  unsigned int r = (u + 0x7fffu + ((u>>16)&1u)) >> 16;
  return (unsigned short)r;
}
__device__ __forceinline__ float bf2f(unsigned short u){
  return __uint_as_float(((unsigned int)u)<<16);
}

// ---------------- weight fp32 [K][N] -> bf16 W^T [N][K] tile transpose ----------------
__device__ __forceinline__ void cvt_tile(const float* __restrict__ src, unsigned short* __restrict__ dst,
                                         int K, int N, int tk, int tn, int tid, float (*s)[33])
{
  int tx = tid & 31, ty0 = tid >> 5;
  #pragma unroll
  for (int it=0; it<4; ++it){
    int ty = ty0 + it*8;
    s[ty][tx] = src[(size_t)(tk*32+ty)*N + tn*32+tx];
  }
  __syncthreads();
  #pragma unroll
  for (int it=0; it<4; ++it){
    int ty = ty0 + it*8;
    dst[(size_t)(tn*32+ty)*K + tk*32 + tx] = f2bf(s[tx][ty]);
  }
}

// ALL weight conversions + bias-fold in one dispatch.
__global__ __launch_bounds__(256) void k_cvtAll(
  const float* __restrict__ win, const float* __restrict__ wmix,
  const float* __restrict__ wf1, const float* __restrict__ wf2,
  const float* __restrict__ tfw2, const float* __restrict__ uhw1, const float* __restrict__ uhw2,
  unsigned short* __restrict__ WtPerm, unsigned short* __restrict__ WtMixT,
  unsigned short* __restrict__ WtH,
  const float* __restrict__ bc, const float* __restrict__ bmix, float* __restrict__ bmixP)
{
  __shared__ float s[32][33];
  int b = blockIdx.x, tid = threadIdx.x;
  if (b < 6912){
    int l = b / 864, r = b % 864;
    if (r < 160)      cvt_tile(win + (size_t)l*163840, WtPerm + (size_t)l*688128,          256, 640,  r/20,      r%20,      tid, s);
    else if (r < 352){int t=r-160; cvt_tile(wmix + (size_t)l*196608, WtMixT + (size_t)l*196608, 768, 256, t/8, t%8, tid, s);}
    else if (r < 608){int t=r-352; cvt_tile(wf1 + (size_t)l*262144, WtPerm + (size_t)l*688128 + 163840, 256, 1024, t/32, t%32, tid, s);}
    else             {int t=r-608; cvt_tile(wf2 + (size_t)l*262144, WtPerm + (size_t)l*688128 + 425984, 1024, 256, t/8, t%8, tid, s);}
  } else if (b < 8000){
    int r = b - 6912;
    if (r < 64)       cvt_tile(tfw2, WtH,        256, 256,  r/8,  r%8,  tid, s);
    else if (r < 832){int t=r-64;  cvt_tile(uhw1, WtH+65536,  768, 1024, t/32, t%32, tid, s);}
    else             {int t=r-832; cvt_tile(uhw2, WtH+851968, 1024, 256, t/8,  t%8,  tid, s);}
  } else {
    // bmixP[l][n] = bmix[l][n] + sum_d bc[l][d] * wmix[l][d][n]
    int l = b - 8000; int n = tid;
    const float* w = wmix + (size_t)l*196608;
    const float* c = bc + l*256;
    float sum = bmix[l*256 + n];
    #pragma unroll 8
    for (int d=0; d<256; d++) sum += c[d]*w[(size_t)d*256 + n];
    bmixP[l*256+n] = sum;
  }
}

// assemble WtBig[l][256 n][640 k]: k<128 from WcombF^T, k>=128 copy wmixT (d=k+128)
__global__ __launch_bounds__(256) void k_asm(
  const float* __restrict__ WcombF, const unsigned short* __restrict__ WtMixT,
  unsigned short* __restrict__ WtBig)
{
  int l = blockIdx.x >> 3, g = blockIdx.x & 7;
  int tid = threadIdx.x;
  int n = g*32 + (tid >> 3);
  int k0 = (tid & 7) * 80;
  const float* wc = WcombF + (size_t)l*32768;
  const unsigned short* wm = WtMixT + (size_t)l*196608 + (size_t)n*768;
  unsigned short* dst = WtBig + (size_t)l*163840 + (size_t)n*640;
  for (int kk=0; kk<80; kk++){
    int k = k0 + kk;
    dst[k] = (k < 128) ? f2bf(wc[(size_t)k*256 + n]) : wm[k+128];
  }
}

// ---------------- legacy fp32-A bf16 MFMA GEMM (prep + tiny head gemms only) ----------------
template<int TN>
__global__ __launch_bounds__(256) void k_gemm_bf(
    const float* __restrict__ A, const unsigned short* __restrict__ Wt,
    const float* __restrict__ bias, float* __restrict__ C,
    int M, int N, int K, int ldA, int ldW, int ldC, int mode,
    size_t sA, size_t sW, size_t sC, size_t sB)
{
  constexpr int NJ = TN/32;
  __shared__ unsigned short Als[128][40];
  __shared__ unsigned short Bls[TN][40];
  int z = blockIdx.z;
  A += (size_t)z*sA; Wt += (size_t)z*sW; C += (size_t)z*sC;
  const float* bz = bias ? bias + (size_t)z*sB : nullptr;
  int tid = threadIdx.x;
  int wave = tid >> 6, lane = tid & 63;
  int wm = (wave >> 1) * 64, wn = (wave & 1) * (TN/2);
  int frow = lane & 15, kg = lane >> 4;
  int bm = blockIdx.y * 128, bn = blockIdx.x * TN;
  int sm = tid >> 1, skh = (tid & 1) * 16;

  floatx4 acc[4][NJ];
  #pragma unroll
  for (int i=0;i<4;i++)
    #pragma unroll
    for (int j=0;j<NJ;j++) acc[i][j] = (floatx4){0.f,0.f,0.f,0.f};

  for (int k0=0; k0<K; k0+=32){
    {
      int gm = bm + sm;
      float f[16];
      if (gm < M){
        const float4* ap = (const float4*)(A + (size_t)gm*ldA + k0 + skh);
        #pragma unroll
        for (int c=0;c<4;c++){ float4 v = ap[c]; f[c*4]=v.x; f[c*4+1]=v.y; f[c*4+2]=v.z; f[c*4+3]=v.w; }
      } else {
        #pragma unroll
        for (int c=0;c<16;c++) f[c]=0.f;
      }
      ushort8 pa, pb;
      #pragma unroll
      for (int c=0;c<8;c++){ pa[c]=f2bf(f[c]); pb[c]=f2bf(f[8+c]); }
      *(ushort8*)&Als[sm][skh]   = pa;
      *(ushort8*)&Als[sm][skh+8] = pb;
    }
    #pragma unroll
    for (int u=0; u<TN/64; u++){
      int li = tid + u*256;
      int row = li >> 2, koff = (li & 3) * 8;
      int gn = bn + row;
      ushort8 wv;
      if (gn < N){
        wv = *(const ushort8*)&Wt[(size_t)gn*ldW + k0 + koff];
      } else {
        for (int c=0;c<8;c++) wv[c]=0;
      }
      *(ushort8*)&Bls[row][koff] = wv;
    }
    __syncthreads();
    short8 af[4], bf[NJ];
    #pragma unroll
    for (int i=0;i<4;i++) af[i] = *(const short8*)&Als[wm + 16*i + frow][kg*8];
    #pragma unroll
    for (int j=0;j<NJ;j++) bf[j] = *(const short8*)&Bls[wn + 16*j + frow][kg*8];
    #pragma unroll
    for (int i=0;i<4;i++)
      #pragma unroll
      for (int j=0;j<NJ;j++)
        acc[i][j] = __builtin_amdgcn_mfma_f32_16x16x32_bf16(af[i], bf[j], acc[i][j], 0, 0, 0);
    __syncthreads();
  }

  #pragma unroll
  for (int j=0;j<NJ;j++){
    int n = bn + wn + 16*j + frow;
    float bv = bz ? bz[n] : 0.f;
    #pragma unroll
    for (int i=0;i<4;i++){
      int m0 = bm + wm + 16*i + kg*4;
      #pragma unroll
      for (int r=0;r<4;r++){
        int m = m0 + r;
        if (m < M){
          float v = acc[i][j][r] + bv;
          if (mode == 1) v = gelu_f(v);
          float* cp = &C[(size_t)m*ldC + n];
          if (mode == 2) v += *cp;
          *cp = v;
        }
      }
    }
  }
}

// ---------------- barrier-free bf16-A GEMM, compile-time K, NJ col-frags per wave ----------------
// grid (N/(64*NJ), M/32); wave w covers cols [bx*64*NJ + w*32*NJ, +32*NJ), rows [by*32, +32).
// mode: 0 = bias, 1 = bias+gelu, 2 = bias+accumulate(fp32), 4 = bias+gelu -> bf16 store
template<int K, int NJ>
__global__ __launch_bounds__(256) void k_gemm16(
    const unsigned short* __restrict__ A, const unsigned short* __restrict__ Wt,
    const float* __restrict__ bias, void* __restrict__ Cv,
    int ldA, int ldW, int ldC, int mode)
{
  int tid = threadIdx.x;
  int wave = tid >> 6, lane = tid & 63;
  int frow = lane & 15, kg = lane >> 4;
  int bm = blockIdx.y * 32;
  int bn = blockIdx.x * (64*NJ) + wave * (16*NJ);

  const unsigned short* a0 = A + (size_t)(bm + frow)*ldA + kg*8;
  const unsigned short* a1 = a0 + (size_t)16*ldA;
  const unsigned short* b0 = Wt + (size_t)(bn + frow)*ldW + kg*8;

  floatx4 acc[2][NJ];
  #pragma unroll
  for (int i=0;i<2;i++)
    #pragma unroll
    for (int j=0;j<NJ;j++) acc[i][j] = (floatx4){0.f,0.f,0.f,0.f};

  #pragma unroll
  for (int k0=0; k0<K; k0+=32){
    short8 af0 = *(const short8*)(a0 + k0);
    short8 af1 = *(const short8*)(a1 + k0);
    #pragma unroll
    for (int j=0;j<NJ;j++){
      short8 bf = *(const short8*)(b0 + (size_t)j*16*ldW + k0);
      acc[0][j] = __builtin_amdgcn_mfma_f32_16x16x32_bf16(af0, bf, acc[0][j], 0, 0, 0);
      acc[1][j] = __builtin_amdgcn_mfma_f32_16x16x32_bf16(af1, bf, acc[1][j], 0, 0, 0);
    }
  }

  float* Cf = (float*)Cv;
  unsigned short* Ch = (unsigned short*)Cv;
  #pragma unroll
  for (int j=0;j<NJ;j++){
    int n = bn + 16*j + frow;
    float bv = bias[n];
    #pragma unroll
    for (int i=0;i<2;i++){
      int m0 = bm + 16*i + kg*4;
      #pragma unroll
      for (int r=0;r<4;r++){
        float v = acc[i][j][r] + bv;
        size_t off = (size_t)(m0+r)*ldC + n;
        if (mode == 1)      Cf[off] = gelu_f(v);
        else if (mode == 2) Cf[off] += v;
        else if (mode == 4) Ch[off] = f2bf(gelu_f(v));
        else                Cf[off] = v;
      }
    }
  }
}

// ---------------- fused proj GEMM (-> gate bf16 + transformed phiQ/phiK/v compact) + dwconv ----------------
// blocks 0..399: gemm rows [by*32,+32), cols [bx*320,+320) (wave covers 80 cols).
// blocks 400..1999: depthwise conv, 4 bt-rows per block.
__global__ __launch_bounds__(256) void k_proj(
  const unsigned short* __restrict__ A, const unsigned short* __restrict__ Wt,
  const float* __restrict__ bias, const int* __restrict__ lens,
  unsigned short* __restrict__ gateb, unsigned short* __restrict__ phiQ,
  unsigned short* __restrict__ phiK, unsigned short* __restrict__ vB,
  const float* __restrict__ tw, const float* __restrict__ tb,
  const float* __restrict__ pw, const float* __restrict__ pb,
  unsigned short* __restrict__ cat)
{
  int bid = blockIdx.x;
  int tid = threadIdx.x;
  if (bid < 400){
    int wave = tid >> 6, lane = tid & 63;
    int frow = lane & 15, kg = lane >> 4;
    int bx = bid & 1, by = bid >> 1;
    int bm = by * 32;
    int wn = bx*320 + wave*80;
    const unsigned short* a0 = A + (size_t)(bm + frow)*256 + kg*8;
    const unsigned short* a1 = a0 + (size_t)16*256;
    const unsigned short* b0 = Wt + (size_t)(wn + frow)*256 + kg*8;
    floatx4 acc[2][5];
    #pragma unroll
    for (int i=0;i<2;i++)
      #pragma unroll
      for (int j=0;j<5;j++) acc[i][j] = (floatx4){0.f,0.f,0.f,0.f};
    #pragma unroll
    for (int k0=0; k0<256; k0+=32){
      short8 af0 = *(const short8*)(a0 + k0);
      short8 af1 = *(const short8*)(a1 + k0);
      #pragma unroll
      for (int j=0;j<5;j++){
        short8 bf = *(const short8*)(b0 + (size_t)j*16*256 + k0);
        acc[0][j] = __builtin_amdgcn_mfma_f32_16x16x32_bf16(af0, bf, acc[0][j], 0, 0, 0);
        acc[1][j] = __builtin_amdgcn_mfma_f32_16x16x32_bf16(af1, bf, acc[1][j], 0, 0, 0);
      }
    }
    #pragma unroll
    for (int i=0;i<2;i++){
      #pragma unroll
      for (int r=0;r<4;r++){
        int row = bm + 16*i + kg*4 + r;
        int t = row % T_, b = row / T_;
        float m = (t >= T_ - lens[b]) ? 1.f : 0.f;
        #pragma unroll
        for (int j=0;j<5;j++){
          int n = wn + 16*j + frow;
          float v = acc[i][j][r] + bias[n];
          if (n < 256){
            gateb[(size_t)row*256 + n] = f2bf(v);
          } else if (n < 384){
            int bh = b*4 + ((n-256)>>5), dd = n & 31;
            phiQ[(size_t)bh*6400 + t*32 + dd] = f2bf((v > 0.f ? v + 1.f : __expf(v))*m);
          } else if (n < 512){
            int bh = b*4 + ((n-384)>>5), dd = n & 31;
            phiK[(size_t)bh*6400 + t*32 + dd] = f2bf((v > 0.f ? v + 1.f : __expf(v))*m);
          } else {
            int bh = b*4 + ((n-512)>>5), dd = n & 31;
            vB[(size_t)bh*6400 + t*32 + dd] = f2bf(v*m);
          }
        }
      }
    }
  } else {
    int bid2 = bid - 400;
    int d = tid;
    int bt0 = bid2*4;
    float xs8[8];
    #pragma unroll
    for (int w=0;w<8;w++){
      int wr = bt0 - 4 + w;
      xs8[w] = (wr >= 0) ? bf2f(A[(size_t)wr*256 + d]) : 0.f;
    }
    #pragma unroll
    for (int rr=0;rr<4;rr++){
      int bt = bt0 + rr, t = bt % T_;
      float ot = tb[d], op = pb[d];
      #pragma unroll
      for (int j=0;j<5;j++){
        int tt = t - 4 + j;
        float xv = (tt >= 0) ? xs8[rr+j] : 0.f;
        op += pw[d*5+j]*xv;
        if (j >= 2) ot += tw[d*3 + (j-2)]*xv;
      }
      cat[(size_t)bt*640 + 128 + d] = f2bf(ot);
      cat[(size_t)bt*640 + 384 + d] = f2bf(op);
    }
  }
}

// ---------------- fused GEMM (N=256 full row) + residual update + LayerNorm (16 rows/block) ----------------
// MODE 0: x = (x + sigmoid(gate)*(acc+bias))*m ; nrm = LN(x) (unmasked)      [mix + postmix]
// MODE 1: x = (x + acc+bias)*m ; nrm = LN(x) * (maskLN ? m : 1)              [ffn2 + addln]
template<int K, int MODE>
__global__ __launch_bounds__(256) void k_gemmln(
    const unsigned short* __restrict__ A, const unsigned short* __restrict__ Wt,
    const float* __restrict__ bias, float* __restrict__ xbuf,
    const unsigned short* __restrict__ gateb, const int* __restrict__ lens,
    const float* __restrict__ g, const float* __restrict__ bb,
    unsigned short* __restrict__ nrm, int maskLN)
{
  __shared__ float rs[16][4];
  __shared__ float rq[16][4];
  int tid = threadIdx.x;
  int wave = tid >> 6, lane = tid & 63;
  int frow = lane & 15, kg = lane >> 4;
  int bm = blockIdx.x * 16;
  int wn = wave * 64;

  const unsigned short* a0 = A + (size_t)(bm + frow)*K + kg*8;
  const unsigned short* b0 = Wt + (size_t)(wn + frow)*K + kg*8;

  floatx4 acc[4];
  #pragma unroll
  for (int j=0;j<4;j++) acc[j] = (floatx4){0.f,0.f,0.f,0.f};

  #pragma unroll
  for (int k0=0; k0<K; k0+=32){
    short8 af0 = *(const short8*)(a0 + k0);
    #pragma unroll
    for (int j=0;j<4;j++){
      short8 bf = *(const short8*)(b0 + (size_t)16*j*K + k0);
      acc[j] = __builtin_amdgcn_mfma_f32_16x16x32_bf16(af0, bf, acc[j], 0, 0, 0);
    }
  }

  float xn[4][4];
  float rowm[4];
  #pragma unroll
  for (int r=0;r<4;r++){
    int row = bm + kg*4 + r;
    int t = row % T_, b = row / T_;
    float m = (t >= T_ - lens[b]) ? 1.f : 0.f;
    rowm[r] = m;
    #pragma unroll
    for (int j=0;j<4;j++){
      int n = wn + 16*j + frow;
      float v = acc[j][r] + bias[n];
      float xv = xbuf[(size_t)row*256 + n];
      float xnv;
      if (MODE == 0){
        float gv = bf2f(gateb[(size_t)row*256 + n]);
        xnv = (xv + v/(1.f+__expf(-gv)))*m;
      } else {
        xnv = (xv + v)*m;
      }
      xn[j][r] = xnv;
      xbuf[(size_t)row*256 + n] = xnv;
    }
  }
  float mu[4];
  #pragma unroll
  for (int r=0;r<4;r++){
    float s = xn[0][r]+xn[1][r]+xn[2][r]+xn[3][r];
    s += __shfl_xor(s,1,64); s += __shfl_xor(s,2,64);
    s += __shfl_xor(s,4,64); s += __shfl_xor(s,8,64);
    if (frow == 0) rs[kg*4 + r][wave] = s;
  }
  __syncthreads();
  #pragma unroll
  for (int r=0;r<4;r++){
    int rl = kg*4 + r;
    mu[r] = (rs[rl][0]+rs[rl][1]+rs[rl][2]+rs[rl][3]) * (1.f/256.f);
  }
  float rstd[4];
  #pragma unroll
  for (int r=0;r<4;r++){
    float m0 = mu[r];
    float s = 0.f;
    #pragma unroll
    for (int j=0;j<4;j++){ float d = xn[j][r]-m0; s += d*d; }
    s += __shfl_xor(s,1,64); s += __shfl_xor(s,2,64);
    s += __shfl_xor(s,4,64); s += __shfl_xor(s,8,64);
    if (frow == 0) rq[kg*4 + r][wave] = s;
  }
  __syncthreads();
  #pragma unroll
  for (int r=0;r<4;r++){
    int rl = kg*4 + r;
    float q = rq[rl][0]+rq[rl][1]+rq[rl][2]+rq[rl][3];
    rstd[r] = rsqrtf(q*(1.f/256.f) + 1e-5f);
  }
  #pragma unroll
  for (int r=0;r<4;r++){
    int row = bm + kg*4 + r;
    float ml = maskLN ? rowm[r] : 1.f;
    #pragma unroll
    for (int j=0;j<4;j++){
      int n = wn + 16*j + frow;
      float h = (xn[j][r]-mu[r])*rstd[r]*g[n] + bb[n];
      nrm[(size_t)row*256 + n] = f2bf(h*ml);
    }
  }
}

// ---------------- embedding + time features (tfh -> bf16) ----------------
__global__ __launch_bounds__(256) void k_embed(
  const int* __restrict__ ids, const int* __restrict__ ts, const int* __restrict__ lens,
  const float* __restrict__ item_emb, const float* __restrict__ pos_emb,
  const float* __restrict__ gap_emb, const float* __restrict__ rec_emb,
  const float* __restrict__ tf_w1, const float* __restrict__ tf_b1,
  float* __restrict__ xbuf, unsigned short* __restrict__ tfh)
{
  int bt = blockIdx.x;
  int b = bt / T_, t = bt % T_;
  int d = threadIdx.x;
  int len = lens[b];
  int tcur = ts[b*T_+t];
  int tlast = ts[b*T_+T_-1];
  bool mask  = t >= T_ - len;
  bool pmask = (t >= 1) && ((t-1) >= T_ - len);
  int gap = 0;
  if (mask && pmask){ int pv = ts[b*T_+t-1]; gap = max(tcur - pv, 0); }
  int rec = mask ? max(tlast - tcur, 0) : 0;
  int gb = min(max((int)floorf(log2f((float)gap + 1.0f)), 0), NB_-1);
  int rb = min(max((int)floorf(log2f((float)rec + 1.0f)), 0), NB_-1);
  float rec_raw = (float)max(tlast - tcur, 0);
  float tf0 = log1pf((float)gb);
  float tf1 = log1pf(rec_raw);
  float hid = gelu_f(tf0*tf_w1[d] + tf1*tf_w1[D_+d] + tf_b1[d]);
  tfh[(size_t)bt*D_ + d] = f2bf(hid);
  int id = ids[b*T_+t];
  xbuf[(size_t)bt*D_ + d] = item_emb[(size_t)id*D_ + d] + pos_emb[t*D_ + d]
                          + gap_emb[gb*D_ + d] + rec_emb[rb*D_ + d];
}

// ---------------- LayerNorm (wave per row), optional bf16 output ----------------
template<int NC>
__global__ __launch_bounds__(256) void k_ln(
  const float* __restrict__ in, void* __restrict__ out,
  const float* __restrict__ g, const float* __restrict__ bb,
  int rows, const int* __restrict__ lens, int applyMask, int outBf)
{
  int wid = threadIdx.x >> 6, lane = threadIdx.x & 63;
  int r = blockIdx.x*4 + wid;
  if (r >= rows) return;
  const int D = NC*256;
  const float4* rp = (const float4*)(in + (size_t)r*D);
  float4 v[NC];
  float s = 0.f;
  #pragma unroll
  for (int c=0;c<NC;c++){ v[c] = rp[c*64 + lane]; s += v[c].x+v[c].y+v[c].z+v[c].w; }
  s = wsum(s);
  float mean = s / (float)D;
  float q = 0.f;
  #pragma unroll
  for (int c=0;c<NC;c++){
    float a=v[c].x-mean, b2=v[c].y-mean, c2=v[c].z-mean, d2=v[c].w-mean;
    q += a*a + b2*b2 + c2*c2 + d2*d2;
  }
  q = wsum(q);
  float rstd = rsqrtf(q/(float)D + 1e-5f);
  float m = 1.f;
  if (applyMask){ int t = r % T_; int b = r / T_; m = (t >= T_ - lens[b]) ? 1.f : 0.f; }
  #pragma unroll
  for (int c=0;c<NC;c++){
    float4 gg  = ((const float4*)g )[c*64+lane];
    float4 bv  = ((const float4*)bb)[c*64+lane];
    float4 o;
    o.x = ((v[c].x-mean)*rstd*gg.x + bv.x)*m;
    o.y = ((v[c].y-mean)*rstd*gg.y + bv.y)*m;
    o.z = ((v[c].z-mean)*rstd*gg.z + bv.z)*m;
    o.w = ((v[c].w-mean)*rstd*gg.w + bv.w)*m;
    if (outBf){
      ushort4v ob; ob.x=f2bf(o.x); ob.y=f2bf(o.y); ob.z=f2bf(o.z); ob.w=f2bf(o.w);
      ((ushort4v*)((unsigned short*)out + (size_t)r*D))[c*64+lane] = ob;
    } else {
      ((float4*)((float*)out + (size_t)r*D))[c*64+lane] = o;
    }
  }
}

// ---------------- fused: x = LN(x,in)*mf (store fp32) ; nrm = LN(x,ln1) -> bf16 ----------------
__global__ __launch_bounds__(256) void k_lnln(
  float* __restrict__ x, const int* __restrict__ lens,
  const float* __restrict__ g1, const float* __restrict__ b1,
  const float* __restrict__ g2, const float* __restrict__ b2,
  unsigned short* __restrict__ nrm)
{
  int wid = threadIdx.x >> 6, lane = threadIdx.x & 63;
  int r = blockIdx.x*4 + wid;
  int t = r % T_, b = r / T_;
  float m = (t >= T_ - lens[b]) ? 1.f : 0.f;
  float4 v = ((const float4*)(x + (size_t)r*256))[lane];
  float s = wsum(v.x+v.y+v.z+v.w);
  float mean = s/256.f;
  float a=v.x-mean, b2v=v.y-mean, c2=v.z-mean, d2=v.w-mean;
  float q = wsum(a*a+b2v*b2v+c2*c2+d2*d2);
  float rstd = rsqrtf(q/256.f + 1e-5f);
  float4 gg = ((const float4*)g1)[lane];
  float4 bv = ((const float4*)b1)[lane];
  float4 xn;
  xn.x = (a*rstd*gg.x + bv.x)*m;
  xn.y = (b2v*rstd*gg.y + bv.y)*m;
  xn.z = (c2*rstd*gg.z + bv.z)*m;
  xn.w = (d2*rstd*gg.w + bv.w)*m;
  ((float4*)(x + (size_t)r*256))[lane] = xn;
  float s2 = wsum(xn.x+xn.y+xn.z+xn.w);
  float mean2 = s2/256.f;
  float a2=xn.x-mean2, b22=xn.y-mean2, c22=xn.z-mean2, d22=xn.w-mean2;
  float q2 = wsum(a2*a2+b22*b22+c22*c22+d22*d22);
  float rstd2 = rsqrtf(q2/256.f + 1e-5f);
  float4 gg2 = ((const float4*)g2)[lane];
  float4 bv2 = ((const float4*)b2)[lane];
  ushort4v o;
  o.x = f2bf(a2*rstd2*gg2.x + bv2.x);
  o.y = f2bf(b22*rstd2*gg2.y + bv2.y);
  o.z = f2bf(c22*rstd2*gg2.z + bv2.z);
  o.w = f2bf(d22*rstd2*gg2.w + bv2.w);
  ((ushort4v*)(nrm + (size_t)r*256))[lane] = o;
}

// ---------------- chunked linear attention, phase A: per-chunk sums (compact bf16 in) ----------------
__global__ __launch_bounds__(128) void k_attn_sums(
  const unsigned short* __restrict__ phiK, const unsigned short* __restrict__ vB,
  float* __restrict__ Ssum)
{
  int blk = blockIdx.x;
  int bh = blk >> 3, c = blk & 7;
  int tid = threadIdx.x; int e = tid & 31, q = tid >> 5;  // q in 0..3
  __shared__ float sk[CH_*32], sv[CH_*32];
  size_t base = (size_t)bh*6400 + (size_t)c*CH_*32;
  for (int idx = tid; idx < CH_*32; idx += 128){
    sk[idx] = bf2f(phiK[base + idx]);
    sv[idx] = bf2f(vB[base + idx]);
  }
  __syncthreads();
  float acc[8];
  #pragma unroll
  for (int j=0;j<8;j++) acc[j]=0.f;
  for (int tl=0; tl<CH_; tl++){
    const float4* k4 = (const float4*)(sk + tl*32 + q*8);
    float vf = sv[tl*32 + e];
    float4 ka = k4[0], kb = k4[1];
    acc[0]+=ka.x*vf; acc[1]+=ka.y*vf; acc[2]+=ka.z*vf; acc[3]+=ka.w*vf;
    acc[4]+=kb.x*vf; acc[5]+=kb.y*vf; acc[6]+=kb.z*vf; acc[7]+=kb.w*vf;
  }
  float* dst = Ssum + ((size_t)bh*8 + c)*1056;
  #pragma unroll
  for (int j=0;j<8;j++) dst[(q*8+j)*32 + e] = acc[j];
  if (q == 0){
    float s = 0.f;
    for (int tl=0; tl<CH_; tl++) s += sk[tl*32 + e];
    dst[1024 + e] = s;
  }
}

// ---------------- phase C: per-chunk outputs -> catb (bf16). inline prefix, compact bf16 in ----------------
__global__ __launch_bounds__(256) void k_attn_out(
  const unsigned short* __restrict__ phiQ, const unsigned short* __restrict__ phiK,
  const unsigned short* __restrict__ vB, const int* __restrict__ lens,
  const float* __restrict__ Ssum, unsigned short* __restrict__ cat)
{
  int blk = blockIdx.x;
  int bh = blk >> 3, c = blk & 7;
  int b = bh >> 2, h = bh & 3;
  int tid = threadIdx.x; int e = tid & 31, qg = tid >> 5;  // qg in 0..7
  int tstart = T_ - lens[b];
  __shared__ float sq[CH_*32], sk[CH_*32], sv[CH_*32];
  __shared__ float P[1056];
  __shared__ float A[CH_][CH_+1];
  __shared__ float sden[CH_];
  int t0 = c*CH_;
  const float* basep = Ssum + (size_t)bh*8*1056;
  for (int idx = tid; idx < 1056; idx += 256){
    float s = 0.f;
    for (int cp=0; cp<c; cp++) s += basep[(size_t)cp*1056 + idx];
    P[idx] = s;
  }
  size_t base = (size_t)bh*6400 + (size_t)c*CH_*32;
  for (int idx = tid; idx < CH_*32; idx += 256){
    sq[idx] = bf2f(phiQ[base + idx]);
    sk[idx] = bf2f(phiK[base + idx]);
    sv[idx] = bf2f(vB[base + idx]);
  }
  __syncthreads();
  for (int idx = tid; idx < CH_*CH_; idx += 256){
    int t = idx / CH_, tp = idx - t*CH_;
    float s = 0.f;
    if (tp <= t){
      const float4* q4 = (const float4*)(sq + t*32);
      const float4* k4 = (const float4*)(sk + tp*32);
      #pragma unroll
      for (int jj=0;jj<8;jj++){
        float4 qq = q4[jj], kk = k4[jj];
        s += qq.x*kk.x + qq.y*kk.y + qq.z*kk.z + qq.w*kk.w;
      }
    }
    A[t][tp] = s;
  }
  __syncthreads();
  if (tid < CH_){
    int t = tid;
    float s = 0.f;
    for (int tp=0; tp<=t; tp++) s += A[t][tp];
    const float* qf = sq + t*32;
    #pragma unroll
    for (int d=0; d<32; d++) s += qf[d]*P[1024+d];
    sden[t] = s;
  }
  __syncthreads();
  int tlo = (qg*CH_) >> 3, thi = ((qg+1)*CH_) >> 3;  // 8 groups covering 0..25
  for (int t = tlo; t < thi; t++){
    float num = 0.f;
    for (int tp=0; tp<=t; tp++) num += A[t][tp]*sv[tp*32+e];
    const float* qf = sq + t*32;
    #pragma unroll
    for (int d=0; d<32; d++) num += qf[d]*P[d*32+e];
    int tg = t0 + t;
    float m = (tg >= tstart) ? 1.f : 0.f;
    cat[(size_t)(b*T_+tg)*640 + h*32 + e] = f2bf(num/(sden[t]+1e-6f)*m);
  }
}

// ---------------- pooling (bf16 x input) ----------------
__global__ __launch_bounds__(256) void k_pool(
  const unsigned short* __restrict__ x, const int* __restrict__ lens,
  const float* __restrict__ pg_w, const float* __restrict__ pg_b,
  float* __restrict__ u0)
{
  int b = blockIdx.x;
  int tid = threadIdx.x, wid = tid>>6, lane = tid&63;
  __shared__ float sps[T_];
  __shared__ float spw[T_];
  int len = lens[b]; int tstart = T_ - len;
  const float4* pw4 = (const float4*)pg_w;
  float4 wv = pw4[lane];
  for (int t = wid; t < T_; t += 4){
    ushort4v xv = ((const ushort4v*)(x + (size_t)(b*T_+t)*D_))[lane];
    float dot = bf2f(xv.x)*wv.x + bf2f(xv.y)*wv.y + bf2f(xv.z)*wv.z + bf2f(xv.w)*wv.w;
    dot = wsum(dot);
    if (lane==0) sps[t] = (t >= tstart) ? dot + pg_b[0] : -1e9f;
  }
  __syncthreads();
  float mx = -1e30f;
  for (int t=0;t<T_;t++) mx = fmaxf(mx, sps[t]);
  float sum = 0.f;
  for (int t=0;t<T_;t++) sum += __expf(sps[t]-mx);
  float inv = 1.f/sum;
  if (tid < T_) spw[tid] = __expf(sps[tid]-mx)*inv;
  __syncthreads();
  int d = tid;
  float macc=0.f, aacc=0.f;
  for (int t=0;t<T_;t++){
    float v = bf2f(x[(size_t)(b*T_+t)*D_ + d]);
    macc += v;
    aacc += spw[t]*v;
  }
  u0[b*768 + d]       = bf2f(x[(size_t)(b*T_+T_-1)*D_ + d]);
  u0[b*768 + 256 + d] = macc / (float)max(len,1);
  u0[b*768 + 512 + d] = aacc;
}

// ---------------- normalize u rows + emit bf16 ----------------
__global__ __launch_bounds__(64) void k_norm(float* __restrict__ u, unsigned short* __restrict__ ub)
{
  int b = blockIdx.x; int lane = threadIdx.x;
  float4* r = (float4*)(u + b*256);
  float4 v = r[lane];
  float ss = v.x*v.x + v.y*v.y + v.z*v.z + v.w*v.w;
  ss = wsum(ss);
  float sc = 1.f/fmaxf(sqrtf(ss), 1e-12f);
  v.x*=sc; v.y*=sc; v.z*=sc; v.w*=sc;
  r[lane]=v;
  ub[b*256 + lane*4 + 0] = f2bf(v.x);
  ub[b*256 + lane*4 + 1] = f2bf(v.y);
  ub[b*256 + lane*4 + 2] = f2bf(v.z);
  ub[b*256 + lane*4 + 3] = f2bf(v.w);
}

// ---------------- barrier-free scoring: per wave 32 items x 32 users ----------------
__global__ __launch_bounds__(256) void k_score2(
  const float* __restrict__ item_emb, const unsigned short* __restrict__ ub,
  const float* __restrict__ item_bias, float* __restrict__ out)
{
  int tid = threadIdx.x;
  int wave = tid >> 6, lane = tid & 63;
  int frow = lane & 15, kg = lane >> 4;
  int n0 = blockIdx.x * 128 + wave * 32;

  int g0 = n0 + frow, g1 = n0 + 16 + frow;
  bool ok0 = g0 < NI_, ok1 = g1 < NI_;
  const float* ip0 = item_emb + (size_t)(g0+1)*256 + kg*8;
  const float* ip1 = item_emb + (size_t)(g1+1)*256 + kg*8;
  const unsigned short* up0 = ub + frow*256 + kg*8;
  const unsigned short* up1 = up0 + 16*256;

  floatx4 acc[2][2];
  #pragma unroll
  for (int i=0;i<2;i++)
    #pragma unroll
    for (int j=0;j<2;j++) acc[i][j] = (floatx4){0.f,0.f,0.f,0.f};
  float ss0 = 0.f, ss1 = 0.f;

  #pragma unroll
  for (int k0=0; k0<256; k0+=32){
    float4 a0, a1, c0, c1;
    if (ok0){ a0 = *(const float4*)(ip0 + k0); a1 = *(const float4*)(ip0 + k0 + 4); }
    else    { a0 = (float4){0,0,0,0}; a1 = a0; }
    if (ok1){ c0 = *(const float4*)(ip1 + k0); c1 = *(const float4*)(ip1 + k0 + 4); }
    else    { c0 = (float4){0,0,0,0}; c1 = c0; }
    ss0 += a0.x*a0.x + a0.y*a0.y + a0.z*a0.z + a0.w*a0.w
         + a1.x*a1.x + a1.y*a1.y + a1.z*a1.z + a1.w*a1.w;
    ss1 += c0.x*c0.x + c0.y*c0.y + c0.z*c0.z + c0.w*c0.w
         + c1.x*c1.x + c1.y*c1.y + c1.z*c1.z + c1.w*c1.w;
    short8 af0, af1;
    af0[0]=(short)f2bf(a0.x); af0[1]=(short)f2bf(a0.y); af0[2]=(short)f2bf(a0.z); af0[3]=(short)f2bf(a0.w);
    af0[4]=(short)f2bf(a1.x); af0[5]=(short)f2bf(a1.y); af0[6]=(short)f2bf(a1.z); af0[7]=(short)f2bf(a1.w);
    af1[0]=(short)f2bf(c0.x); af1[1]=(short)f2bf(c0.y); af1[2]=(short)f2bf(c0.z); af1[3]=(short)f2bf(c0.w);
    af1[4]=(short)f2bf(c1.x); af1[5]=(short)f2bf(c1.y); af1[6]=(short)f2bf(c1.z); af1[7]=(short)f2bf(c1.w);
    short8 bf0 = *(const short8*)(up0 + k0);
    short8 bf1 = *(const short8*)(up1 + k0);
    acc[0][0] = __builtin_amdgcn_mfma_f32_16x16x32_bf16(af0, bf0, acc[0][0], 0, 0, 0);
    acc[0][1] = __builtin_amdgcn_mfma_f32_16x16x32_bf16(af0, bf1, acc[0][1], 0, 0, 0);
    acc[1][0] = __builtin_amdgcn_mfma_f32_16x16x32_bf16(af1, bf0, acc[1][0], 0, 0, 0);
    acc[1][1] = __builtin_amdgcn_mfma_f32_16x16x32_bf16(af1, bf1, acc[1][1], 0, 0, 0);
  }

  ss0 += __shfl_xor(ss0, 16, 64); ss0 += __shfl_xor(ss0, 32, 64);
  ss1 += __shfl_xor(ss1, 16, 64); ss1 += __shfl_xor(ss1, 32, 64);

  #pragma unroll
  for (int i=0;i<2;i++){
    int nb = n0 + 16*i + kg*4;
    if (nb >= NI_) continue;
    float ssr = i ? ss1 : ss0;
    float sc[4], bv[4];
    #pragma unroll
    for (int r=0;r<4;r++){
      float ssv = __shfl(ssr, kg*4 + r, 64);
      sc[r] = 1.f/fmaxf(sqrtf(ssv), 1e-12f);
      bv[r] = item_bias[nb + r + 1];
    }
    #pragma unroll
    for (int j=0;j<2;j++){
      int row = 16*j + frow;
      float4 o;
      o.x = acc[i][j][0]*sc[0] + bv[0];
      o.y = acc[i][j][1]*sc[1] + bv[1];
      o.z = acc[i][j][2]*sc[2] + bv[2];
      o.w = acc[i][j][3]*sc[3] + bv[3];
      *(float4*)&out[(size_t)row*NI_ + nb] = o;
    }
  }
}

extern "C" void kernel_launch(void* const* d_in, const int* in_sizes, int n_in,
                              void* d_out, int out_size, void* d_ws, size_t ws_size,
                              hipStream_t stream)
{
  const int* ids  = (const int*)d_in[0];
  const int* ts   = (const int*)d_in[1];
  const int* lens = (const int*)d_in[2];
  const float* item_emb = (const float*)d_in[3];
  const float* pos_emb  = (const float*)d_in[4];
  const float* gap_emb  = (const float*)d_in[5];
  const float* rec_emb  = (const float*)d_in[6];
  const float* tf_w1 = (const float*)d_in[7];
  const float* tf_b1 = (const float*)d_in[8];
  const float* tf_w2 = (const float*)d_in[9];
  const float* tf_b2 = (const float*)d_in[10];
  const float* in_g  = (const float*)d_in[11];
  const float* in_b  = (const float*)d_in[12];
  const float* l_ln1g = (const float*)d_in[13];
  const float* l_ln1b = (const float*)d_in[14];
  const float* l_win  = (const float*)d_in[15];
  const float* l_bin  = (const float*)d_in[16];
  const float* l_wc   = (const float*)d_in[17];
  const float* l_bc   = (const float*)d_in[18];
  const float* l_tw   = (const float*)d_in[19];
  const float* l_tb   = (const float*)d_in[20];
  const float* l_pw   = (const float*)d_in[21];
  const float* l_pb   = (const float*)d_in[22];
  const float* l_wmix = (const float*)d_in[23];
  const float* l_bmix = (const float*)d_in[24];
  const float* l_ln2g = (const float*)d_in[25];
  const float* l_ln2b = (const float*)d_in[26];
  const float* l_wf1  = (const float*)d_in[27];
  const float* l_bf1  = (const float*)d_in[28];
  const float* l_wf2  = (const float*)d_in[29];
  const float* l_bf2  = (const float*)d_in[30];
  const float* fn_g = (const float*)d_in[31];
  const float* fn_b = (const float*)d_in[32];
  const float* pg_w = (const float*)d_in[33];
  const float* pg_b = (const float*)d_in[34];
  const float* uh_w1 = (const float*)d_in[35];
  const float* uh_b1 = (const float*)d_in[36];
  const float* uh_lng = (const float*)d_in[37];
  const float* uh_lnb = (const float*)d_in[38];
  const float* uh_w2 = (const float*)d_in[39];
  const float* uh_b2 = (const float*)d_in[40];
  const float* item_bias = (const float*)d_in[41];
  float* out = (float*)d_out;

  const int MT = B_*T_;
  float* ws   = (float*)d_ws;
  float* xbuf = ws;                               // 1,638,400
  float* tmp  = xbuf + (size_t)MT*D_;             // 1,638,400 (tmpb bf16 lives here)
  float* proj = tmp  + (size_t)MT*D_;             // 4,096,000 (gateb/phi bf16 live here)
  float* cat  = proj + (size_t)MT*640;            // 4,096,000 (catb bf16 lives here)
  float* mid  = cat  + (size_t)MT*640;            // 6,553,600 (midb bf16 lives here)
  float* u0   = mid  + (size_t)MT*FF_;            // 24,576
  float* u1   = u0 + 32*768;                      // 32,768
  float* u2   = u1 + 32*1024;                     // 8,192
  float* WcombF = u2 + 32*256;                    // 262,144 (8 x 128 x 256)
  float* bmixP  = WcombF + 262144;                // 2,048
  float* Ssum   = bmixP + 2048;                   // 1,081,344 (128 bh x 8 c x 1056)
  unsigned short* WtPerm = (unsigned short*)(Ssum + 1081344);  // 5,505,024 ush
  unsigned short* WtMixT = WtPerm + 5505024;      // 1,572,864 ush
  unsigned short* WtBig  = WtMixT + 1572864;      // 1,310,720 ush
  unsigned short* WtH    = WtBig  + 1310720;      // 1,114,112 ush
  unsigned short* u2b    = WtH    + 1114112;      // 8,192 ush

  unsigned short* tmpb = (unsigned short*)tmp;                    // 6400x256 bf16
  unsigned short* catb = (unsigned short*)cat;                    // 6400x640 bf16
  unsigned short* midb = (unsigned short*)(mid + (size_t)MT*D_);  // 6400x1024 bf16
  unsigned short* gateb = (unsigned short*)proj;                  // 6400x256 bf16
  unsigned short* phiQ  = gateb + 1638400;                        // 128x200x32 bf16
  unsigned short* phiK  = phiQ + 819200;
  unsigned short* vBuf  = phiK + 819200;

  // ---- weight prep (one-time per launch) ----
  k_cvtAll<<<8008, 256, 0, stream>>>(l_win, l_wmix, l_wf1, l_wf2, tf_w2, uh_w1, uh_w2,
                                     WtPerm, WtMixT, WtH, l_bc, l_bmix, bmixP);
  k_gemm_bf<64><<<dim3(4,1,8), 256, 0, stream>>>(l_wc, WtMixT, nullptr, WcombF,
                                                 128, 256, 256, 256, 768, 256, 0,
                                                 (size_t)128*256, (size_t)196608, (size_t)32768, 0);
  k_asm<<<64, 256, 0, stream>>>(WcombF, WtMixT, WtBig);

  // ---- embedding + dense time ----
  k_embed<<<MT, 256, 0, stream>>>(ids, ts, lens, item_emb, pos_emb, gap_emb, rec_emb,
                                  tf_w1, tf_b1, xbuf, tmpb);
  k_gemm16<256,2><<<dim3(2,200), 256, 0, stream>>>(tmpb, WtH, tf_b2, xbuf, 256, 256, 256, 2);
  k_lnln<<<MT/4, 256, 0, stream>>>(xbuf, lens, in_g, in_b, l_ln1g, l_ln1b, tmpb);

  // ---- layers ----
  for (int i=0;i<L_;i++){
    const unsigned short* WL = WtPerm + (size_t)i*688128;
    k_proj<<<2000, 256, 0, stream>>>(tmpb, WL, l_bin+i*640, lens,
                                     gateb, phiQ, phiK, vBuf,
                                     l_tw+i*768, l_tb+i*256, l_pw+i*1280, l_pb+i*256, catb);
    k_attn_sums<<<B_*H_*8, 128, 0, stream>>>(phiK, vBuf, Ssum);
    k_attn_out<<<B_*H_*8, 256, 0, stream>>>(phiQ, phiK, vBuf, lens, Ssum, catb);
    k_gemmln<640,0><<<400, 256, 0, stream>>>(catb, WtBig+(size_t)i*163840, bmixP+i*256,
                                             xbuf, gateb, lens,
                                             l_ln2g+i*256, l_ln2b+i*256, tmpb, 0);
    k_gemm16<256,4><<<dim3(4,200), 256, 0, stream>>>(tmpb, WL+163840, l_bf1+i*FF_, midb,
                                                     256, 256, FF_, 4);
    bool last = (i == L_-1);
    k_gemmln<1024,1><<<400, 256, 0, stream>>>(midb, WL+425984, l_bf2+i*256,
                                              xbuf, nullptr, lens,
                                              last ? fn_g : l_ln1g+(i+1)*256,
                                              last ? fn_b : l_ln1b+(i+1)*256,
                                              tmpb, last ? 1 : 0);
  }

  // ---- pooling + user head (final LN'd x is in tmpb, bf16) ----
  k_pool<<<B_, 256, 0, stream>>>(tmpb, lens, pg_w, pg_b, u0);
  k_gemm_bf<128><<<dim3(8,1), 256, 0, stream>>>(u0, WtH+65536, uh_b1, u1,
                                                32, 1024, 768, 768, 768, 1024, 1, 0,0,0,0);
  k_ln<4><<<8, 256, 0, stream>>>(u1, u1, uh_lng, uh_lnb, 32, lens, 0, 0);
  k_gemm_bf<64><<<dim3(4,1), 256, 0, stream>>>(u1, WtH+851968, uh_b2, u2,
                                               32, 256, 1024, 1024, 1024, 256, 0, 0,0,0,0);
  k_norm<<<B_, 64, 0, stream>>>(u2, u2b);

  // ---- scoring ----
  k_score2<<<(NI_+127)/128, 256, 0, stream>>>(item_emb, u2b, item_bias, out);
}

// Round 6
// 1601.527 us; speedup vs baseline: 1.0531x; 1.0531x over previous
//
#include <hip/hip_runtime.h>
#include <math.h>

#define B_ 32
#define T_ 200
#define D_ 256
#define H_ 4
#define DH_ 32
#define INNER_ 128
#define L_ 8
#define FF_ 1024
#define NI_ 100000
#define NB_ 64
#define CH_ 25

typedef __attribute__((ext_vector_type(8))) short short8;
typedef __attribute__((ext_vector_type(8))) unsigned short ushort8;
typedef __attribute__((ext_vector_type(4))) unsigned short ushort4v;
typedef __attribute__((ext_vector_type(4))) float floatx4;

__device__ __forceinline__ float gelu_f(float x){
  return 0.5f*x*(1.0f+erff(x*0.70710678118654752f));
}
__device__ __forceinline__ float wsum(float v){
  #pragma unroll
  for (int o=32;o>0;o>>=1) v += __shfl_xor(v,o,64);
  return v;
}
__device__ __forceinline__ unsigned short f2bf(float x){
  unsigned int u = __float_as_uint(x);
  unsigned int r = (u + 0x7fffu + ((u>>16)&1u)) >> 16;
  return (unsigned short)r;
}
__device__ __forceinline__ float bf2f(unsigned short u){
  return __uint_as_float(((unsigned int)u)<<16);
}

// ---------------- weight fp32 [K][N] -> bf16 W^T [N][K] tile transpose ----------------
__device__ __forceinline__ void cvt_tile(const float* __restrict__ src, unsigned short* __restrict__ dst,
                                         int K, int N, int tk, int tn, int tid, float (*s)[33])
{
  int tx = tid & 31, ty0 = tid >> 5;
  #pragma unroll
  for (int it=0; it<4; ++it){
    int ty = ty0 + it*8;
    s[ty][tx] = src[(size_t)(tk*32+ty)*N + tn*32+tx];
  }
  __syncthreads();
  #pragma unroll
  for (int it=0; it<4; ++it){
    int ty = ty0 + it*8;
    dst[(size_t)(tn*32+ty)*K + tk*32 + tx] = f2bf(s[tx][ty]);
  }
}

// ALL weight conversions + bias-fold in one dispatch.
__global__ __launch_bounds__(256) void k_cvtAll(
  const float* __restrict__ win, const float* __restrict__ wmix,
  const float* __restrict__ wf1, const float* __restrict__ wf2,
  const float* __restrict__ tfw2, const float* __restrict__ uhw1, const float* __restrict__ uhw2,
  unsigned short* __restrict__ WtPerm, unsigned short* __restrict__ WtMixT,
  unsigned short* __restrict__ WtH,
  const float* __restrict__ bc, const float* __restrict__ bmix, float* __restrict__ bmixP)
{
  __shared__ float s[32][33];
  int b = blockIdx.x, tid = threadIdx.x;
  if (b < 6912){
    int l = b / 864, r = b % 864;
    if (r < 160)      cvt_tile(win + (size_t)l*163840, WtPerm + (size_t)l*688128,          256, 640,  r/20,      r%20,      tid, s);
    else if (r < 352){int t=r-160; cvt_tile(wmix + (size_t)l*196608, WtMixT + (size_t)l*196608, 768, 256, t/8, t%8, tid, s);}
    else if (r < 608){int t=r-352; cvt_tile(wf1 + (size_t)l*262144, WtPerm + (size_t)l*688128 + 163840, 256, 1024, t/32, t%32, tid, s);}
    else             {int t=r-608; cvt_tile(wf2 + (size_t)l*262144, WtPerm + (size_t)l*688128 + 425984, 1024, 256, t/8, t%8, tid, s);}
  } else if (b < 8000){
    int r = b - 6912;
    if (r < 64)       cvt_tile(tfw2, WtH,        256, 256,  r/8,  r%8,  tid, s);
    else if (r < 832){int t=r-64;  cvt_tile(uhw1, WtH+65536,  768, 1024, t/32, t%32, tid, s);}
    else             {int t=r-832; cvt_tile(uhw2, WtH+851968, 1024, 256, t/8,  t%8,  tid, s);}
  } else {
    int l = b - 8000; int n = tid;
    const float* w = wmix + (size_t)l*196608;
    const float* c = bc + l*256;
    float sum = bmix[l*256 + n];
    #pragma unroll 8
    for (int d=0; d<256; d++) sum += c[d]*w[(size_t)d*256 + n];
    bmixP[l*256+n] = sum;
  }
}

// assemble WtBig[l][256 n][640 k]: k<128 from WcombF^T, k>=128 copy wmixT (d=k+128)
__global__ __launch_bounds__(256) void k_asm(
  const float* __restrict__ WcombF, const unsigned short* __restrict__ WtMixT,
  unsigned short* __restrict__ WtBig)
{
  int l = blockIdx.x >> 3, g = blockIdx.x & 7;
  int tid = threadIdx.x;
  int n = g*32 + (tid >> 3);
  int k0 = (tid & 7) * 80;
  const float* wc = WcombF + (size_t)l*32768;
  const unsigned short* wm = WtMixT + (size_t)l*196608 + (size_t)n*768;
  unsigned short* dst = WtBig + (size_t)l*163840 + (size_t)n*640;
  for (int kk=0; kk<80; kk++){
    int k = k0 + kk;
    dst[k] = (k < 128) ? f2bf(wc[(size_t)k*256 + n]) : wm[k+128];
  }
}

// ---------------- legacy fp32-A bf16 MFMA GEMM (prep + tiny head gemms only) ----------------
template<int TN>
__global__ __launch_bounds__(256) void k_gemm_bf(
    const float* __restrict__ A, const unsigned short* __restrict__ Wt,
    const float* __restrict__ bias, float* __restrict__ C,
    int M, int N, int K, int ldA, int ldW, int ldC, int mode,
    size_t sA, size_t sW, size_t sC, size_t sB)
{
  constexpr int NJ = TN/32;
  __shared__ unsigned short Als[128][40];
  __shared__ unsigned short Bls[TN][40];
  int z = blockIdx.z;
  A += (size_t)z*sA; Wt += (size_t)z*sW; C += (size_t)z*sC;
  const float* bz = bias ? bias + (size_t)z*sB : nullptr;
  int tid = threadIdx.x;
  int wave = tid >> 6, lane = tid & 63;
  int wm = (wave >> 1) * 64, wn = (wave & 1) * (TN/2);
  int frow = lane & 15, kg = lane >> 4;
  int bm = blockIdx.y * 128, bn = blockIdx.x * TN;
  int sm = tid >> 1, skh = (tid & 1) * 16;

  floatx4 acc[4][NJ];
  #pragma unroll
  for (int i=0;i<4;i++)
    #pragma unroll
    for (int j=0;j<NJ;j++) acc[i][j] = (floatx4){0.f,0.f,0.f,0.f};

  for (int k0=0; k0<K; k0+=32){
    {
      int gm = bm + sm;
      float f[16];
      if (gm < M){
        const float4* ap = (const float4*)(A + (size_t)gm*ldA + k0 + skh);
        #pragma unroll
        for (int c=0;c<4;c++){ float4 v = ap[c]; f[c*4]=v.x; f[c*4+1]=v.y; f[c*4+2]=v.z; f[c*4+3]=v.w; }
      } else {
        #pragma unroll
        for (int c=0;c<16;c++) f[c]=0.f;
      }
      ushort8 pa, pb;
      #pragma unroll
      for (int c=0;c<8;c++){ pa[c]=f2bf(f[c]); pb[c]=f2bf(f[8+c]); }
      *(ushort8*)&Als[sm][skh]   = pa;
      *(ushort8*)&Als[sm][skh+8] = pb;
    }
    #pragma unroll
    for (int u=0; u<TN/64; u++){
      int li = tid + u*256;
      int row = li >> 2, koff = (li & 3) * 8;
      int gn = bn + row;
      ushort8 wv;
      if (gn < N){
        wv = *(const ushort8*)&Wt[(size_t)gn*ldW + k0 + koff];
      } else {
        for (int c=0;c<8;c++) wv[c]=0;
      }
      *(ushort8*)&Bls[row][koff] = wv;
    }
    __syncthreads();
    short8 af[4], bf[NJ];
    #pragma unroll
    for (int i=0;i<4;i++) af[i] = *(const short8*)&Als[wm + 16*i + frow][kg*8];
    #pragma unroll
    for (int j=0;j<NJ;j++) bf[j] = *(const short8*)&Bls[wn + 16*j + frow][kg*8];
    #pragma unroll
    for (int i=0;i<4;i++)
      #pragma unroll
      for (int j=0;j<NJ;j++)
        acc[i][j] = __builtin_amdgcn_mfma_f32_16x16x32_bf16(af[i], bf[j], acc[i][j], 0, 0, 0);
    __syncthreads();
  }

  #pragma unroll
  for (int j=0;j<NJ;j++){
    int n = bn + wn + 16*j + frow;
    float bv = bz ? bz[n] : 0.f;
    #pragma unroll
    for (int i=0;i<4;i++){
      int m0 = bm + wm + 16*i + kg*4;
      #pragma unroll
      for (int r=0;r<4;r++){
        int m = m0 + r;
        if (m < M){
          float v = acc[i][j][r] + bv;
          if (mode == 1) v = gelu_f(v);
          float* cp = &C[(size_t)m*ldC + n];
          if (mode == 2) v += *cp;
          *cp = v;
        }
      }
    }
  }
}

// ---------------- barrier-free bf16-A GEMM, compile-time K, NJ col-frags per wave ----------------
template<int K, int NJ>
__global__ __launch_bounds__(256) void k_gemm16(
    const unsigned short* __restrict__ A, const unsigned short* __restrict__ Wt,
    const float* __restrict__ bias, void* __restrict__ Cv,
    int ldA, int ldW, int ldC, int mode)
{
  int tid = threadIdx.x;
  int wave = tid >> 6, lane = tid & 63;
  int frow = lane & 15, kg = lane >> 4;
  int bm = blockIdx.y * 32;
  int bn = blockIdx.x * (64*NJ) + wave * (16*NJ);

  const unsigned short* a0 = A + (size_t)(bm + frow)*ldA + kg*8;
  const unsigned short* a1 = a0 + (size_t)16*ldA;
  const unsigned short* b0 = Wt + (size_t)(bn + frow)*ldW + kg*8;

  floatx4 acc[2][NJ];
  #pragma unroll
  for (int i=0;i<2;i++)
    #pragma unroll
    for (int j=0;j<NJ;j++) acc[i][j] = (floatx4){0.f,0.f,0.f,0.f};

  #pragma unroll
  for (int k0=0; k0<K; k0+=32){
    short8 af0 = *(const short8*)(a0 + k0);
    short8 af1 = *(const short8*)(a1 + k0);
    #pragma unroll
    for (int j=0;j<NJ;j++){
      short8 bf = *(const short8*)(b0 + (size_t)j*16*ldW + k0);
      acc[0][j] = __builtin_amdgcn_mfma_f32_16x16x32_bf16(af0, bf, acc[0][j], 0, 0, 0);
      acc[1][j] = __builtin_amdgcn_mfma_f32_16x16x32_bf16(af1, bf, acc[1][j], 0, 0, 0);
    }
  }

  float* Cf = (float*)Cv;
  unsigned short* Ch = (unsigned short*)Cv;
  #pragma unroll
  for (int j=0;j<NJ;j++){
    int n = bn + 16*j + frow;
    float bv = bias[n];
    #pragma unroll
    for (int i=0;i<2;i++){
      int m0 = bm + 16*i + kg*4;
      #pragma unroll
      for (int r=0;r<4;r++){
        float v = acc[i][j][r] + bv;
        size_t off = (size_t)(m0+r)*ldC + n;
        if (mode == 1)      Cf[off] = gelu_f(v);
        else if (mode == 2) Cf[off] += v;
        else if (mode == 4) Ch[off] = f2bf(gelu_f(v));
        else                Cf[off] = v;
      }
    }
  }
}

// ---------------- fused proj GEMM (16 rows/block) + dwconv ----------------
// blocks 0..799: gemm rows [by*16,+16), cols [bx*320,+320) (wave covers 80 cols).
// blocks 800..2399: depthwise conv, 4 bt-rows per block.
__global__ __launch_bounds__(256) void k_proj(
  const unsigned short* __restrict__ A, const unsigned short* __restrict__ Wt,
  const float* __restrict__ bias, const int* __restrict__ lens,
  unsigned short* __restrict__ gateb, unsigned short* __restrict__ phiQ,
  unsigned short* __restrict__ phiK, unsigned short* __restrict__ vB,
  const float* __restrict__ tw, const float* __restrict__ tb,
  const float* __restrict__ pw, const float* __restrict__ pb,
  unsigned short* __restrict__ cat)
{
  int bid = blockIdx.x;
  int tid = threadIdx.x;
  if (bid < 800){
    int wave = tid >> 6, lane = tid & 63;
    int frow = lane & 15, kg = lane >> 4;
    int bx = bid & 1, by = bid >> 1;
    int bm = by * 16;
    int wn = bx*320 + wave*80;
    const unsigned short* a0 = A + (size_t)(bm + frow)*256 + kg*8;
    const unsigned short* b0 = Wt + (size_t)(wn + frow)*256 + kg*8;
    floatx4 acc[5];
    #pragma unroll
    for (int j=0;j<5;j++) acc[j] = (floatx4){0.f,0.f,0.f,0.f};
    #pragma unroll
    for (int k0=0; k0<256; k0+=32){
      short8 af0 = *(const short8*)(a0 + k0);
      #pragma unroll
      for (int j=0;j<5;j++){
        short8 bf = *(const short8*)(b0 + (size_t)j*16*256 + k0);
        acc[j] = __builtin_amdgcn_mfma_f32_16x16x32_bf16(af0, bf, acc[j], 0, 0, 0);
      }
    }
    #pragma unroll
    for (int r=0;r<4;r++){
      int row = bm + kg*4 + r;
      int t = row % T_, b = row / T_;
      float m = (t >= T_ - lens[b]) ? 1.f : 0.f;
      #pragma unroll
      for (int j=0;j<5;j++){
        int n = wn + 16*j + frow;
        float v = acc[j][r] + bias[n];
        if (n < 256){
          gateb[(size_t)row*256 + n] = f2bf(v);
        } else if (n < 384){
          int bh = b*4 + ((n-256)>>5), dd = n & 31;
          phiQ[(size_t)bh*6400 + t*32 + dd] = f2bf((v > 0.f ? v + 1.f : __expf(v))*m);
        } else if (n < 512){
          int bh = b*4 + ((n-384)>>5), dd = n & 31;
          phiK[(size_t)bh*6400 + t*32 + dd] = f2bf((v > 0.f ? v + 1.f : __expf(v))*m);
        } else {
          int bh = b*4 + ((n-512)>>5), dd = n & 31;
          vB[(size_t)bh*6400 + t*32 + dd] = f2bf(v*m);
        }
      }
    }
  } else {
    int bid2 = bid - 800;
    int d = tid;
    int bt0 = bid2*4;
    float xs8[8];
    #pragma unroll
    for (int w=0;w<8;w++){
      int wr = bt0 - 4 + w;
      xs8[w] = (wr >= 0) ? bf2f(A[(size_t)wr*256 + d]) : 0.f;
    }
    #pragma unroll
    for (int rr=0;rr<4;rr++){
      int bt = bt0 + rr, t = bt % T_;
      float ot = tb[d], op = pb[d];
      #pragma unroll
      for (int j=0;j<5;j++){
        int tt = t - 4 + j;
        float xv = (tt >= 0) ? xs8[rr+j] : 0.f;
        op += pw[d*5+j]*xv;
        if (j >= 2) ot += tw[d*3 + (j-2)]*xv;
      }
      cat[(size_t)bt*640 + 128 + d] = f2bf(ot);
      cat[(size_t)bt*640 + 384 + d] = f2bf(op);
    }
  }
}

// ---------------- fused attention: inline kv-prefix + per-chunk outputs -> catb ----------------
__global__ __launch_bounds__(256) void k_attn_fused(
  const unsigned short* __restrict__ phiQ, const unsigned short* __restrict__ phiK,
  const unsigned short* __restrict__ vB, const int* __restrict__ lens,
  unsigned short* __restrict__ cat)
{
  int blk = blockIdx.x;
  int bh = blk >> 3, c = blk & 7;
  int b = bh >> 2, h = bh & 3;
  int tid = threadIdx.x; int e = tid & 31, qg = tid >> 5;
  int tstart = T_ - lens[b];
  __shared__ float sq[CH_*32], sk[CH_*32], sv[CH_*32];
  __shared__ float P[1056];
  __shared__ float A[CH_][CH_+1];
  __shared__ float sden[CH_];
  int t0 = c*CH_;
  size_t bbase = (size_t)bh*6400;
  // prefix kv[d][e] and ksum[e] over chunks < c, rebuilt from phiK/vB
  float pkv0=0.f, pkv1=0.f, pkv2=0.f, pkv3=0.f, pks=0.f;
  int dd = tid >> 3;             // d for P entries tid*4..tid*4+3
  int e0 = (tid*4) & 31;
  for (int cp=0; cp<c; cp++){
    size_t pbase = bbase + (size_t)cp*800;
    for (int idx=tid; idx<800; idx+=256){
      sk[idx] = bf2f(phiK[pbase+idx]);
      sv[idx] = bf2f(vB[pbase+idx]);
    }
    __syncthreads();
    #pragma unroll 5
    for (int tl=0; tl<CH_; tl++){
      float kd = sk[tl*32+dd];
      pkv0 += kd*sv[tl*32+e0];
      pkv1 += kd*sv[tl*32+e0+1];
      pkv2 += kd*sv[tl*32+e0+2];
      pkv3 += kd*sv[tl*32+e0+3];
    }
    if (tid < 32){
      float s = 0.f;
      for (int tl=0; tl<CH_; tl++) s += sk[tl*32+tid];
      pks += s;
    }
    __syncthreads();
  }
  P[tid*4+0]=pkv0; P[tid*4+1]=pkv1; P[tid*4+2]=pkv2; P[tid*4+3]=pkv3;
  if (tid < 32) P[1024+tid] = pks;
  // own chunk
  size_t base = bbase + (size_t)c*800;
  for (int idx=tid; idx<800; idx+=256){
    sq[idx] = bf2f(phiQ[base+idx]);
    sk[idx] = bf2f(phiK[base+idx]);
    sv[idx] = bf2f(vB[base+idx]);
  }
  __syncthreads();
  for (int idx = tid; idx < CH_*CH_; idx += 256){
    int t = idx / CH_, tp = idx - t*CH_;
    float s = 0.f;
    if (tp <= t){
      const float4* q4 = (const float4*)(sq + t*32);
      const float4* k4 = (const float4*)(sk + tp*32);
      #pragma unroll
      for (int jj=0;jj<8;jj++){
        float4 qq = q4[jj], kk = k4[jj];
        s += qq.x*kk.x + qq.y*kk.y + qq.z*kk.z + qq.w*kk.w;
      }
    }
    A[t][tp] = s;
  }
  __syncthreads();
  if (tid < CH_){
    int t = tid;
    float s = 0.f;
    for (int tp=0; tp<=t; tp++) s += A[t][tp];
    const float* qf = sq + t*32;
    #pragma unroll
    for (int d=0; d<32; d++) s += qf[d]*P[1024+d];
    sden[t] = s;
  }
  __syncthreads();
  int tlo = (qg*CH_) >> 3, thi = ((qg+1)*CH_) >> 3;
  for (int t = tlo; t < thi; t++){
    float num = 0.f;
    for (int tp=0; tp<=t; tp++) num += A[t][tp]*sv[tp*32+e];
    const float* qf = sq + t*32;
    #pragma unroll
    for (int d=0; d<32; d++) num += qf[d]*P[d*32+e];
    int tg = t0 + t;
    float m = (tg >= tstart) ? 1.f : 0.f;
    cat[(size_t)(b*T_+tg)*640 + h*32 + e] = f2bf(num/(sden[t]+1e-6f)*m);
  }
}

// ---------------- fused MLP: mix-GEMM + gate-residual + LN2 + ffn1(gelu) + ffn2 + residual + LN ----------------
// grid 400, 256 thr; block owns 16 rows. wave covers 64 cols in phases A/C, 256 cols in phase B.
__global__ __launch_bounds__(256) void k_mlp(
  const unsigned short* __restrict__ catA, const unsigned short* __restrict__ Wmix,
  const float* __restrict__ bmix, float* __restrict__ xbuf,
  const unsigned short* __restrict__ gateb, const int* __restrict__ lens,
  const float* __restrict__ g2, const float* __restrict__ b2,
  const unsigned short* __restrict__ W1t, const float* __restrict__ bf1,
  const unsigned short* __restrict__ W2t, const float* __restrict__ bf2,
  const float* __restrict__ gn, const float* __restrict__ bn2,
  unsigned short* __restrict__ nrm, int maskLN)
{
  __shared__ unsigned short hb[16][264];     // LN2 output bf16 (pad 8)
  __shared__ unsigned short ms[16][1032];    // gelu mid bf16 (pad 8)
  __shared__ float rs[16][4];
  __shared__ float rq[16][4];
  int tid = threadIdx.x;
  int wave = tid >> 6, lane = tid & 63;
  int frow = lane & 15, kg = lane >> 4;
  int bm = blockIdx.x * 16;
  int wn = wave * 64;

  // ---- Phase A: mix GEMM K=640 ----
  const unsigned short* a0 = catA + (size_t)(bm + frow)*640 + kg*8;
  const unsigned short* b0 = Wmix + (size_t)(wn + frow)*640 + kg*8;
  floatx4 acc[4];
  #pragma unroll
  for (int j=0;j<4;j++) acc[j] = (floatx4){0.f,0.f,0.f,0.f};
  #pragma unroll
  for (int k0=0; k0<640; k0+=32){
    short8 af = *(const short8*)(a0 + k0);
    #pragma unroll
    for (int j=0;j<4;j++){
      short8 bf = *(const short8*)(b0 + (size_t)j*16*640 + k0);
      acc[j] = __builtin_amdgcn_mfma_f32_16x16x32_bf16(af, bf, acc[j], 0, 0, 0);
    }
  }
  // gate residual (x kept in registers xm)
  float xm[4][4];
  float rowm[4];
  #pragma unroll
  for (int r=0;r<4;r++){
    int row = bm + kg*4 + r;
    int t = row % T_, b = row / T_;
    float m = (t >= T_ - lens[b]) ? 1.f : 0.f;
    rowm[r] = m;
    #pragma unroll
    for (int j=0;j<4;j++){
      int n = wn + 16*j + frow;
      float v = acc[j][r] + bmix[n];
      float xv = xbuf[(size_t)row*256 + n];
      float gv = bf2f(gateb[(size_t)row*256 + n]);
      xm[j][r] = (xv + v/(1.f+__expf(-gv)))*m;
    }
  }
  // LN2 (cross-wave 2-barrier reduction)
  float mu[4], rstd[4];
  #pragma unroll
  for (int r=0;r<4;r++){
    float s = xm[0][r]+xm[1][r]+xm[2][r]+xm[3][r];
    s += __shfl_xor(s,1,64); s += __shfl_xor(s,2,64);
    s += __shfl_xor(s,4,64); s += __shfl_xor(s,8,64);
    if (frow == 0) rs[kg*4 + r][wave] = s;
  }
  __syncthreads();
  #pragma unroll
  for (int r=0;r<4;r++){
    int rl = kg*4 + r;
    mu[r] = (rs[rl][0]+rs[rl][1]+rs[rl][2]+rs[rl][3]) * (1.f/256.f);
  }
  #pragma unroll
  for (int r=0;r<4;r++){
    float m0 = mu[r];
    float s = 0.f;
    #pragma unroll
    for (int j=0;j<4;j++){ float d = xm[j][r]-m0; s += d*d; }
    s += __shfl_xor(s,1,64); s += __shfl_xor(s,2,64);
    s += __shfl_xor(s,4,64); s += __shfl_xor(s,8,64);
    if (frow == 0) rq[kg*4 + r][wave] = s;
  }
  __syncthreads();
  #pragma unroll
  for (int r=0;r<4;r++){
    int rl = kg*4 + r;
    float q = rq[rl][0]+rq[rl][1]+rq[rl][2]+rq[rl][3];
    rstd[r] = rsqrtf(q*(1.f/256.f) + 1e-5f);
  }
  #pragma unroll
  for (int r=0;r<4;r++){
    #pragma unroll
    for (int j=0;j<4;j++){
      int n = wn + 16*j + frow;
      float hh = (xm[j][r]-mu[r])*rstd[r]*g2[n] + b2[n];
      hb[kg*4+r][n] = f2bf(hh);
    }
  }
  __syncthreads();

  // ---- Phase B: ffn1 K=256, wave covers 256 cols (8 pairs) ----
  #pragma unroll 2
  for (int jo=0; jo<8; jo++){
    int nA = wave*256 + jo*32 + frow;
    int nB = nA + 16;
    const unsigned short* bpA = W1t + (size_t)nA*256 + kg*8;
    const unsigned short* bpB = W1t + (size_t)nB*256 + kg*8;
    floatx4 fA = (floatx4){0.f,0.f,0.f,0.f};
    floatx4 fB = (floatx4){0.f,0.f,0.f,0.f};
    #pragma unroll
    for (int k0=0; k0<256; k0+=32){
      short8 af = *(const short8*)&hb[frow][kg*8 + k0];
      short8 b1v = *(const short8*)(bpA + k0);
      short8 b2v = *(const short8*)(bpB + k0);
      fA = __builtin_amdgcn_mfma_f32_16x16x32_bf16(af, b1v, fA, 0, 0, 0);
      fB = __builtin_amdgcn_mfma_f32_16x16x32_bf16(af, b2v, fB, 0, 0, 0);
    }
    float bbA = bf1[nA], bbB = bf1[nB];
    #pragma unroll
    for (int r=0;r<4;r++){
      ms[kg*4+r][nA] = f2bf(gelu_f(fA[r] + bbA));
      ms[kg*4+r][nB] = f2bf(gelu_f(fB[r] + bbB));
    }
  }
  __syncthreads();

  // ---- Phase C: ffn2 K=1024, wave covers 64 cols ----
  floatx4 f2[4];
  #pragma unroll
  for (int j=0;j<4;j++) f2[j] = (floatx4){0.f,0.f,0.f,0.f};
  const unsigned short* c0 = W2t + (size_t)(wn + frow)*1024 + kg*8;
  #pragma unroll
  for (int k0=0; k0<1024; k0+=32){
    short8 af = *(const short8*)&ms[frow][kg*8 + k0];
    #pragma unroll
    for (int j=0;j<4;j++){
      short8 bf = *(const short8*)(c0 + (size_t)j*16*1024 + k0);
      f2[j] = __builtin_amdgcn_mfma_f32_16x16x32_bf16(af, bf, f2[j], 0, 0, 0);
    }
  }
  // residual + final LN (next-layer ln1 or fn)
  float xn2[4][4];
  #pragma unroll
  for (int r=0;r<4;r++){
    int row = bm + kg*4 + r;
    #pragma unroll
    for (int j=0;j<4;j++){
      int n = wn + 16*j + frow;
      float v = f2[j][r] + bf2[n];
      float xnv = (xm[j][r] + v)*rowm[r];
      xn2[j][r] = xnv;
      xbuf[(size_t)row*256 + n] = xnv;
    }
  }
  float mu2[4], rstd2[4];
  #pragma unroll
  for (int r=0;r<4;r++){
    float s = xn2[0][r]+xn2[1][r]+xn2[2][r]+xn2[3][r];
    s += __shfl_xor(s,1,64); s += __shfl_xor(s,2,64);
    s += __shfl_xor(s,4,64); s += __shfl_xor(s,8,64);
    if (frow == 0) rs[kg*4 + r][wave] = s;
  }
  __syncthreads();
  #pragma unroll
  for (int r=0;r<4;r++){
    int rl = kg*4 + r;
    mu2[r] = (rs[rl][0]+rs[rl][1]+rs[rl][2]+rs[rl][3]) * (1.f/256.f);
  }
  #pragma unroll
  for (int r=0;r<4;r++){
    float m0 = mu2[r];
    float s = 0.f;
    #pragma unroll
    for (int j=0;j<4;j++){ float d = xn2[j][r]-m0; s += d*d; }
    s += __shfl_xor(s,1,64); s += __shfl_xor(s,2,64);
    s += __shfl_xor(s,4,64); s += __shfl_xor(s,8,64);
    if (frow == 0) rq[kg*4 + r][wave] = s;
  }
  __syncthreads();
  #pragma unroll
  for (int r=0;r<4;r++){
    int rl = kg*4 + r;
    float q = rq[rl][0]+rq[rl][1]+rq[rl][2]+rq[rl][3];
    rstd2[r] = rsqrtf(q*(1.f/256.f) + 1e-5f);
  }
  #pragma unroll
  for (int r=0;r<4;r++){
    int row = bm + kg*4 + r;
    float ml = maskLN ? rowm[r] : 1.f;
    #pragma unroll
    for (int j=0;j<4;j++){
      int n = wn + 16*j + frow;
      float hh = (xn2[j][r]-mu2[r])*rstd2[r]*gn[n] + bn2[n];
      nrm[(size_t)row*256 + n] = f2bf(hh*ml);
    }
  }
}

// ---------------- embedding + time features (tfh -> bf16) ----------------
__global__ __launch_bounds__(256) void k_embed(
  const int* __restrict__ ids, const int* __restrict__ ts, const int* __restrict__ lens,
  const float* __restrict__ item_emb, const float* __restrict__ pos_emb,
  const float* __restrict__ gap_emb, const float* __restrict__ rec_emb,
  const float* __restrict__ tf_w1, const float* __restrict__ tf_b1,
  float* __restrict__ xbuf, unsigned short* __restrict__ tfh)
{
  int bt = blockIdx.x;
  int b = bt / T_, t = bt % T_;
  int d = threadIdx.x;
  int len = lens[b];
  int tcur = ts[b*T_+t];
  int tlast = ts[b*T_+T_-1];
  bool mask  = t >= T_ - len;
  bool pmask = (t >= 1) && ((t-1) >= T_ - len);
  int gap = 0;
  if (mask && pmask){ int pv = ts[b*T_+t-1]; gap = max(tcur - pv, 0); }
  int rec = mask ? max(tlast - tcur, 0) : 0;
  int gb = min(max((int)floorf(log2f((float)gap + 1.0f)), 0), NB_-1);
  int rb = min(max((int)floorf(log2f((float)rec + 1.0f)), 0), NB_-1);
  float rec_raw = (float)max(tlast - tcur, 0);
  float tf0 = log1pf((float)gb);
  float tf1 = log1pf(rec_raw);
  float hid = gelu_f(tf0*tf_w1[d] + tf1*tf_w1[D_+d] + tf_b1[d]);
  tfh[(size_t)bt*D_ + d] = f2bf(hid);
  int id = ids[b*T_+t];
  xbuf[(size_t)bt*D_ + d] = item_emb[(size_t)id*D_ + d] + pos_emb[t*D_ + d]
                          + gap_emb[gb*D_ + d] + rec_emb[rb*D_ + d];
}

// ---------------- LayerNorm (wave per row), optional bf16 output ----------------
template<int NC>
__global__ __launch_bounds__(256) void k_ln(
  const float* __restrict__ in, void* __restrict__ out,
  const float* __restrict__ g, const float* __restrict__ bb,
  int rows, const int* __restrict__ lens, int applyMask, int outBf)
{
  int wid = threadIdx.x >> 6, lane = threadIdx.x & 63;
  int r = blockIdx.x*4 + wid;
  if (r >= rows) return;
  const int D = NC*256;
  const float4* rp = (const float4*)(in + (size_t)r*D);
  float4 v[NC];
  float s = 0.f;
  #pragma unroll
  for (int c=0;c<NC;c++){ v[c] = rp[c*64 + lane]; s += v[c].x+v[c].y+v[c].z+v[c].w; }
  s = wsum(s);
  float mean = s / (float)D;
  float q = 0.f;
  #pragma unroll
  for (int c=0;c<NC;c++){
    float a=v[c].x-mean, b2=v[c].y-mean, c2=v[c].z-mean, d2=v[c].w-mean;
    q += a*a + b2*b2 + c2*c2 + d2*d2;
  }
  q = wsum(q);
  float rstd = rsqrtf(q/(float)D + 1e-5f);
  float m = 1.f;
  if (applyMask){ int t = r % T_; int b = r / T_; m = (t >= T_ - lens[b]) ? 1.f : 0.f; }
  #pragma unroll
  for (int c=0;c<NC;c++){
    float4 gg  = ((const float4*)g )[c*64+lane];
    float4 bv  = ((const float4*)bb)[c*64+lane];
    float4 o;
    o.x = ((v[c].x-mean)*rstd*gg.x + bv.x)*m;
    o.y = ((v[c].y-mean)*rstd*gg.y + bv.y)*m;
    o.z = ((v[c].z-mean)*rstd*gg.z + bv.z)*m;
    o.w = ((v[c].w-mean)*rstd*gg.w + bv.w)*m;
    if (outBf){
      ushort4v ob; ob.x=f2bf(o.x); ob.y=f2bf(o.y); ob.z=f2bf(o.z); ob.w=f2bf(o.w);
      ((ushort4v*)((unsigned short*)out + (size_t)r*D))[c*64+lane] = ob;
    } else {
      ((float4*)((float*)out + (size_t)r*D))[c*64+lane] = o;
    }
  }
}

// ---------------- fused: x = LN(x,in)*mf (store fp32) ; nrm = LN(x,ln1) -> bf16 ----------------
__global__ __launch_bounds__(256) void k_lnln(
  float* __restrict__ x, const int* __restrict__ lens,
  const float* __restrict__ g1, const float* __restrict__ b1,
  const float* __restrict__ g2, const float* __restrict__ b2,
  unsigned short* __restrict__ nrm)
{
  int wid = threadIdx.x >> 6, lane = threadIdx.x & 63;
  int r = blockIdx.x*4 + wid;
  int t = r % T_, b = r / T_;
  float m = (t >= T_ - lens[b]) ? 1.f : 0.f;
  float4 v = ((const float4*)(x + (size_t)r*256))[lane];
  float s = wsum(v.x+v.y+v.z+v.w);
  float mean = s/256.f;
  float a=v.x-mean, b2v=v.y-mean, c2=v.z-mean, d2=v.w-mean;
  float q = wsum(a*a+b2v*b2v+c2*c2+d2*d2);
  float rstd = rsqrtf(q/256.f + 1e-5f);
  float4 gg = ((const float4*)g1)[lane];
  float4 bv = ((const float4*)b1)[lane];
  float4 xn;
  xn.x = (a*rstd*gg.x + bv.x)*m;
  xn.y = (b2v*rstd*gg.y + bv.y)*m;
  xn.z = (c2*rstd*gg.z + bv.z)*m;
  xn.w = (d2*rstd*gg.w + bv.w)*m;
  ((float4*)(x + (size_t)r*256))[lane] = xn;
  float s2 = wsum(xn.x+xn.y+xn.z+xn.w);
  float mean2 = s2/256.f;
  float a2=xn.x-mean2, b22=xn.y-mean2, c22=xn.z-mean2, d22=xn.w-mean2;
  float q2 = wsum(a2*a2+b22*b22+c22*c22+d22*d22);
  float rstd2 = rsqrtf(q2/256.f + 1e-5f);
  float4 gg2 = ((const float4*)g2)[lane];
  float4 bv2 = ((const float4*)b2)[lane];
  ushort4v o;
  o.x = f2bf(a2*rstd2*gg2.x + bv2.x);
  o.y = f2bf(b22*rstd2*gg2.y + bv2.y);
  o.z = f2bf(c22*rstd2*gg2.z + bv2.z);
  o.w = f2bf(d22*rstd2*gg2.w + bv2.w);
  ((ushort4v*)(nrm + (size_t)r*256))[lane] = o;
}

// ---------------- pooling (bf16 x input) ----------------
__global__ __launch_bounds__(256) void k_pool(
  const unsigned short* __restrict__ x, const int* __restrict__ lens,
  const float* __restrict__ pg_w, const float* __restrict__ pg_b,
  float* __restrict__ u0)
{
  int b = blockIdx.x;
  int tid = threadIdx.x, wid = tid>>6, lane = tid&63;
  __shared__ float sps[T_];
  __shared__ float spw[T_];
  int len = lens[b]; int tstart = T_ - len;
  const float4* pw4 = (const float4*)pg_w;
  float4 wv = pw4[lane];
  for (int t = wid; t < T_; t += 4){
    ushort4v xv = ((const ushort4v*)(x + (size_t)(b*T_+t)*D_))[lane];
    float dot = bf2f(xv.x)*wv.x + bf2f(xv.y)*wv.y + bf2f(xv.z)*wv.z + bf2f(xv.w)*wv.w;
    dot = wsum(dot);
    if (lane==0) sps[t] = (t >= tstart) ? dot + pg_b[0] : -1e9f;
  }
  __syncthreads();
  float mx = -1e30f;
  for (int t=0;t<T_;t++) mx = fmaxf(mx, sps[t]);
  float sum = 0.f;
  for (int t=0;t<T_;t++) sum += __expf(sps[t]-mx);
  float inv = 1.f/sum;
  if (tid < T_) spw[tid] = __expf(sps[tid]-mx)*inv;
  __syncthreads();
  int d = tid;
  float macc=0.f, aacc=0.f;
  for (int t=0;t<T_;t++){
    float v = bf2f(x[(size_t)(b*T_+t)*D_ + d]);
    macc += v;
    aacc += spw[t]*v;
  }
  u0[b*768 + d]       = bf2f(x[(size_t)(b*T_+T_-1)*D_ + d]);
  u0[b*768 + 256 + d] = macc / (float)max(len,1);
  u0[b*768 + 512 + d] = aacc;
}

// ---------------- normalize u rows + emit bf16 ----------------
__global__ __launch_bounds__(64) void k_norm(float* __restrict__ u, unsigned short* __restrict__ ub)
{
  int b = blockIdx.x; int lane = threadIdx.x;
  float4* r = (float4*)(u + b*256);
  float4 v = r[lane];
  float ss = v.x*v.x + v.y*v.y + v.z*v.z + v.w*v.w;
  ss = wsum(ss);
  float sc = 1.f/fmaxf(sqrtf(ss), 1e-12f);
  v.x*=sc; v.y*=sc; v.z*=sc; v.w*=sc;
  r[lane]=v;
  ub[b*256 + lane*4 + 0] = f2bf(v.x);
  ub[b*256 + lane*4 + 1] = f2bf(v.y);
  ub[b*256 + lane*4 + 2] = f2bf(v.z);
  ub[b*256 + lane*4 + 3] = f2bf(v.w);
}

// ---------------- barrier-free scoring: per wave 32 items x 32 users ----------------
__global__ __launch_bounds__(256) void k_score2(
  const float* __restrict__ item_emb, const unsigned short* __restrict__ ub,
  const float* __restrict__ item_bias, float* __restrict__ out)
{
  int tid = threadIdx.x;
  int wave = tid >> 6, lane = tid & 63;
  int frow = lane & 15, kg = lane >> 4;
  int n0 = blockIdx.x * 128 + wave * 32;

  int g0 = n0 + frow, g1 = n0 + 16 + frow;
  bool ok0 = g0 < NI_, ok1 = g1 < NI_;
  const float* ip0 = item_emb + (size_t)(g0+1)*256 + kg*8;
  const float* ip1 = item_emb + (size_t)(g1+1)*256 + kg*8;
  const unsigned short* up0 = ub + frow*256 + kg*8;
  const unsigned short* up1 = up0 + 16*256;

  floatx4 acc[2][2];
  #pragma unroll
  for (int i=0;i<2;i++)
    #pragma unroll
    for (int j=0;j<2;j++) acc[i][j] = (floatx4){0.f,0.f,0.f,0.f};
  float ss0 = 0.f, ss1 = 0.f;

  #pragma unroll
  for (int k0=0; k0<256; k0+=32){
    float4 a0, a1, c0, c1;
    if (ok0){ a0 = *(const float4*)(ip0 + k0); a1 = *(const float4*)(ip0 + k0 + 4); }
    else    { a0 = (float4){0,0,0,0}; a1 = a0; }
    if (ok1){ c0 = *(const float4*)(ip1 + k0); c1 = *(const float4*)(ip1 + k0 + 4); }
    else    { c0 = (float4){0,0,0,0}; c1 = c0; }
    ss0 += a0.x*a0.x + a0.y*a0.y + a0.z*a0.z + a0.w*a0.w
         + a1.x*a1.x + a1.y*a1.y + a1.z*a1.z + a1.w*a1.w;
    ss1 += c0.x*c0.x + c0.y*c0.y + c0.z*c0.z + c0.w*c0.w
         + c1.x*c1.x + c1.y*c1.y + c1.z*c1.z + c1.w*c1.w;
    short8 af0, af1;
    af0[0]=(short)f2bf(a0.x); af0[1]=(short)f2bf(a0.y); af0[2]=(short)f2bf(a0.z); af0[3]=(short)f2bf(a0.w);
    af0[4]=(short)f2bf(a1.x); af0[5]=(short)f2bf(a1.y); af0[6]=(short)f2bf(a1.z); af0[7]=(short)f2bf(a1.w);
    af1[0]=(short)f2bf(c0.x); af1[1]=(short)f2bf(c0.y); af1[2]=(short)f2bf(c0.z); af1[3]=(short)f2bf(c0.w);
    af1[4]=(short)f2bf(c1.x); af1[5]=(short)f2bf(c1.y); af1[6]=(short)f2bf(c1.z); af1[7]=(short)f2bf(c1.w);
    short8 bf0 = *(const short8*)(up0 + k0);
    short8 bf1 = *(const short8*)(up1 + k0);
    acc[0][0] = __builtin_amdgcn_mfma_f32_16x16x32_bf16(af0, bf0, acc[0][0], 0, 0, 0);
    acc[0][1] = __builtin_amdgcn_mfma_f32_16x16x32_bf16(af0, bf1, acc[0][1], 0, 0, 0);
    acc[1][0] = __builtin_amdgcn_mfma_f32_16x16x32_bf16(af1, bf0, acc[1][0], 0, 0, 0);
    acc[1][1] = __builtin_amdgcn_mfma_f32_16x16x32_bf16(af1, bf1, acc[1][1], 0, 0, 0);
  }

  ss0 += __shfl_xor(ss0, 16, 64); ss0 += __shfl_xor(ss0, 32, 64);
  ss1 += __shfl_xor(ss1, 16, 64); ss1 += __shfl_xor(ss1, 32, 64);

  #pragma unroll
  for (int i=0;i<2;i++){
    int nb = n0 + 16*i + kg*4;
    if (nb >= NI_) continue;
    float ssr = i ? ss1 : ss0;
    float sc[4], bv[4];
    #pragma unroll
    for (int r=0;r<4;r++){
      float ssv = __shfl(ssr, kg*4 + r, 64);
      sc[r] = 1.f/fmaxf(sqrtf(ssv), 1e-12f);
      bv[r] = item_bias[nb + r + 1];
    }
    #pragma unroll
    for (int j=0;j<2;j++){
      int row = 16*j + frow;
      float4 o;
      o.x = acc[i][j][0]*sc[0] + bv[0];
      o.y = acc[i][j][1]*sc[1] + bv[1];
      o.z = acc[i][j][2]*sc[2] + bv[2];
      o.w = acc[i][j][3]*sc[3] + bv[3];
      *(float4*)&out[(size_t)row*NI_ + nb] = o;
    }
  }
}

extern "C" void kernel_launch(void* const* d_in, const int* in_sizes, int n_in,
                              void* d_out, int out_size, void* d_ws, size_t ws_size,
                              hipStream_t stream)
{
  const int* ids  = (const int*)d_in[0];
  const int* ts   = (const int*)d_in[1];
  const int* lens = (const int*)d_in[2];
  const float* item_emb = (const float*)d_in[3];
  const float* pos_emb  = (const float*)d_in[4];
  const float* gap_emb  = (const float*)d_in[5];
  const float* rec_emb  = (const float*)d_in[6];
  const float* tf_w1 = (const float*)d_in[7];
  const float* tf_b1 = (const float*)d_in[8];
  const float* tf_w2 = (const float*)d_in[9];
  const float* tf_b2 = (const float*)d_in[10];
  const float* in_g  = (const float*)d_in[11];
  const float* in_b  = (const float*)d_in[12];
  const float* l_ln1g = (const float*)d_in[13];
  const float* l_ln1b = (const float*)d_in[14];
  const float* l_win  = (const float*)d_in[15];
  const float* l_bin  = (const float*)d_in[16];
  const float* l_wc   = (const float*)d_in[17];
  const float* l_bc   = (const float*)d_in[18];
  const float* l_tw   = (const float*)d_in[19];
  const float* l_tb   = (const float*)d_in[20];
  const float* l_pw   = (const float*)d_in[21];
  const float* l_pb   = (const float*)d_in[22];
  const float* l_wmix = (const float*)d_in[23];
  const float* l_bmix = (const float*)d_in[24];
  const float* l_ln2g = (const float*)d_in[25];
  const float* l_ln2b = (const float*)d_in[26];
  const float* l_wf1  = (const float*)d_in[27];
  const float* l_bf1  = (const float*)d_in[28];
  const float* l_wf2  = (const float*)d_in[29];
  const float* l_bf2  = (const float*)d_in[30];
  const float* fn_g = (const float*)d_in[31];
  const float* fn_b = (const float*)d_in[32];
  const float* pg_w = (const float*)d_in[33];
  const float* pg_b = (const float*)d_in[34];
  const float* uh_w1 = (const float*)d_in[35];
  const float* uh_b1 = (const float*)d_in[36];
  const float* uh_lng = (const float*)d_in[37];
  const float* uh_lnb = (const float*)d_in[38];
  const float* uh_w2 = (const float*)d_in[39];
  const float* uh_b2 = (const float*)d_in[40];
  const float* item_bias = (const float*)d_in[41];
  float* out = (float*)d_out;

  const int MT = B_*T_;
  float* ws   = (float*)d_ws;
  float* xbuf = ws;                               // 1,638,400
  float* tmp  = xbuf + (size_t)MT*D_;             // 1,638,400 (tmpb bf16 lives here)
  float* proj = tmp  + (size_t)MT*D_;             // 4,096,000 (gateb/phi bf16 live here)
  float* cat  = proj + (size_t)MT*640;            // 4,096,000 (catb bf16 lives here)
  float* mid  = cat  + (size_t)MT*640;            // 6,553,600 (unused mid region)
  float* u0   = mid  + (size_t)MT*FF_;            // 24,576
  float* u1   = u0 + 32*768;                      // 32,768
  float* u2   = u1 + 32*1024;                     // 8,192
  float* WcombF = u2 + 32*256;                    // 262,144 (8 x 128 x 256)
  float* bmixP  = WcombF + 262144;                // 2,048
  float* Ssum   = bmixP + 2048;                   // 1,081,344 (unused now)
  unsigned short* WtPerm = (unsigned short*)(Ssum + 1081344);  // 5,505,024 ush
  unsigned short* WtMixT = WtPerm + 5505024;      // 1,572,864 ush
  unsigned short* WtBig  = WtMixT + 1572864;      // 1,310,720 ush
  unsigned short* WtH    = WtBig  + 1310720;      // 1,114,112 ush
  unsigned short* u2b    = WtH    + 1114112;      // 8,192 ush

  unsigned short* tmpb = (unsigned short*)tmp;                    // 6400x256 bf16
  unsigned short* catb = (unsigned short*)cat;                    // 6400x640 bf16
  unsigned short* gateb = (unsigned short*)proj;                  // 6400x256 bf16
  unsigned short* phiQ  = gateb + 1638400;                        // 128x200x32 bf16
  unsigned short* phiK  = phiQ + 819200;
  unsigned short* vBuf  = phiK + 819200;

  // ---- weight prep (one-time per launch) ----
  k_cvtAll<<<8008, 256, 0, stream>>>(l_win, l_wmix, l_wf1, l_wf2, tf_w2, uh_w1, uh_w2,
                                     WtPerm, WtMixT, WtH, l_bc, l_bmix, bmixP);
  k_gemm_bf<64><<<dim3(4,1,8), 256, 0, stream>>>(l_wc, WtMixT, nullptr, WcombF,
                                                 128, 256, 256, 256, 768, 256, 0,
                                                 (size_t)128*256, (size_t)196608, (size_t)32768, 0);
  k_asm<<<64, 256, 0, stream>>>(WcombF, WtMixT, WtBig);

  // ---- embedding + dense time ----
  k_embed<<<MT, 256, 0, stream>>>(ids, ts, lens, item_emb, pos_emb, gap_emb, rec_emb,
                                  tf_w1, tf_b1, xbuf, tmpb);
  k_gemm16<256,2><<<dim3(2,200), 256, 0, stream>>>(tmpb, WtH, tf_b2, xbuf, 256, 256, 256, 2);
  k_lnln<<<MT/4, 256, 0, stream>>>(xbuf, lens, in_g, in_b, l_ln1g, l_ln1b, tmpb);

  // ---- layers: 3 dispatches each ----
  for (int i=0;i<L_;i++){
    const unsigned short* WL = WtPerm + (size_t)i*688128;
    bool last = (i == L_-1);
    k_proj<<<2400, 256, 0, stream>>>(tmpb, WL, l_bin+i*640, lens,
                                     gateb, phiQ, phiK, vBuf,
                                     l_tw+i*768, l_tb+i*256, l_pw+i*1280, l_pb+i*256, catb);
    k_attn_fused<<<B_*H_*8, 256, 0, stream>>>(phiQ, phiK, vBuf, lens, catb);
    k_mlp<<<400, 256, 0, stream>>>(catb, WtBig+(size_t)i*163840, bmixP+i*256,
                                   xbuf, gateb, lens,
                                   l_ln2g+i*256, l_ln2b+i*256,
                                   WL+163840, l_bf1+i*FF_,
                                   WL+425984, l_bf2+i*256,
                                   last ? fn_g : l_ln1g+(i+1)*256,
                                   last ? fn_b : l_ln1b+(i+1)*256,
                                   tmpb, last ? 1 : 0);
  }

  // ---- pooling + user head (final LN'd x is in tmpb, bf16) ----
  k_pool<<<B_, 256, 0, stream>>>(tmpb, lens, pg_w, pg_b, u0);
  k_gemm_bf<128><<<dim3(8,1), 256, 0, stream>>>(u0, WtH+65536, uh_b1, u1,
                                                32, 1024, 768, 768, 768, 1024, 1, 0,0,0,0);
  k_ln<4><<<8, 256, 0, stream>>>(u1, u1, uh_lng, uh_lnb, 32, lens, 0, 0);
  k_gemm_bf<64><<<dim3(4,1), 256, 0, stream>>>(u1, WtH+851968, uh_b2, u2,
                                               32, 256, 1024, 1024, 1024, 256, 0, 0,0,0,0);
  k_norm<<<B_, 64, 0, stream>>>(u2, u2b);

  // ---- scoring ----
  k_score2<<<(NI_+127)/128, 256, 0, stream>>>(item_emb, u2b, item_bias, out);
}